// Round 20
// baseline (272.072 us; speedup 1.0000x reference)
//
#include <hip/hip_runtime.h>
#include <hip/hip_bf16.h>

#define D_ 768
#define E_ 8
#define H_ 3072
#define N_TOK 4096
#define BT 64
#define BK 64

typedef _Float16 f16;
typedef f16 f16x8 __attribute__((ext_vector_type(8)));
typedef float f32x4 __attribute__((ext_vector_type(4)));

__device__ __forceinline__ void gld16(const f16* g, f16* l) {
    __builtin_amdgcn_global_load_lds(
        (const __attribute__((address_space(1))) unsigned int*)g,
        (__attribute__((address_space(3))) unsigned int*)l, 16, 0, 0);
}

__device__ __forceinline__ int prefix_off(const int* counts, int e, int* cnt_out) {
    int off = 0, cnt = 0;
#pragma unroll
    for (int q = 0; q < E_; q++) {
        int cq = counts[q];
        if (q < e) off += cq;
        if (q == e) cnt = cq;
    }
    *cnt_out = cnt;
    return off;
}

// ---------------- router: coalesced GEMV + LDS-aggregated atomics ----------------
__global__ __launch_bounds__(1024) void router(const float* __restrict__ x,
                                               const float* __restrict__ gw,
                                               const float* __restrict__ gb,
                                               int* __restrict__ counts,
                                               int* __restrict__ list,
                                               float* __restrict__ wslot) {
    __shared__ int lcount[E_];
    __shared__ int lbase[E_];
    __shared__ int te0[64], te1[64], ts0[64], ts1[64];
    __shared__ float tw0[64], tw1[64];

    int tid = threadIdx.x;
    int wv = tid >> 6, lane = tid & 63;
    int s = lane >> 3, eL = lane & 7;
    if (tid < E_) lcount[tid] = 0;
    __syncthreads();

    float biasL = gb[eL];

#pragma unroll 1
    for (int i = 0; i < 4; i++) {
        int lt = wv * 4 + i;
        int tok = blockIdx.x * 64 + lt;
        const float* xr = x + (size_t)tok * D_;
        float a = 0.f;
        const float* gwl = gw + lane;
#pragma unroll 8
        for (int j = 0; j < 96; j++)
            a = fmaf(xr[j * 8 + s], gwl[j * 64], a);
        a += __shfl_xor(a, 8, 64);
        a += __shfl_xor(a, 16, 64);
        a += __shfl_xor(a, 32, 64);
        float lg = a + biasL;
        float le[8];
#pragma unroll
        for (int q = 0; q < 8; q++) le[q] = __shfl(lg, q, 64);
        float v0 = -3.4e38f, v1 = -3.4e38f;
        int i0 = 0, i1 = 0;
#pragma unroll
        for (int q = 0; q < 8; q++) {
            float l = le[q];
            if (l > v0) { v1 = v0; i1 = i0; v0 = l; i0 = q; }
            else if (l > v1) { v1 = l; i1 = q; }
        }
        if (lane == 0) {
            float p1 = expf(v1 - v0);
            float ssum = 1.f + p1;
            int s0 = atomicAdd(&lcount[i0], 1);
            int s1 = atomicAdd(&lcount[i1], 1);
            te0[lt] = i0; ts0[lt] = s0; tw0[lt] = 1.f / ssum;
            te1[lt] = i1; ts1[lt] = s1; tw1[lt] = p1 / ssum;
        }
    }
    __syncthreads();
    if (tid < E_) lbase[tid] = atomicAdd(&counts[tid], lcount[tid]);
    __syncthreads();
    if (tid < 64) {
        int tok = blockIdx.x * 64 + tid;
        int e0 = te0[tid], e1 = te1[tid];
        list[e0 * N_TOK + lbase[e0] + ts0[tid]] = tok * 2;
        list[e1 * N_TOK + lbase[e1] + ts1[tid]] = tok * 2 + 1;
        wslot[tok * 2] = tw0[tid];
        wslot[tok * 2 + 1] = tw1[tid];
    }
}

// ---------------- prep: fused weight-convert (blocks 0..9215) + pack_a ----------------
#define CVT_BLKS 9216   // 576 * 16
__global__ __launch_bounds__(256) void prep(const float* __restrict__ w1,
                                            const float* __restrict__ w2,
                                            f16* __restrict__ w1t,
                                            f16* __restrict__ w2t,
                                            const float* __restrict__ x,
                                            const int* __restrict__ counts,
                                            const int* __restrict__ list,
                                            f16* __restrict__ xg) {
    __shared__ f16 t[64][66];
    int bid = blockIdx.x;
    int tid = threadIdx.x;

    if (bid < CVT_BLKS) {
        int z = bid / 576;
        int bx = bid % 576;
        const float* src; f16* dst; int R, C, xb, yb;
        if (z < E_) {
            src = w1 + (size_t)z * D_ * H_; dst = w1t + (size_t)z * D_ * H_;
            R = D_; C = H_; xb = bx % 48; yb = bx / 48;
        } else {
            src = w2 + (size_t)(z - E_) * H_ * D_; dst = w2t + (size_t)(z - E_) * H_ * D_;
            R = H_; C = D_; xb = bx % 12; yb = bx / 12;
        }
        int r0 = yb * 64, c0 = xb * 64;
        {
            int r = tid >> 4;
            int c = (tid & 15) * 4;
#pragma unroll
            for (int i = 0; i < 4; i++) {
                float4 v = *(const float4*)(src + (size_t)(r0 + r + i * 16) * C + (c0 + c));
                t[r + i * 16][c] = (f16)v.x;
                t[r + i * 16][c + 1] = (f16)v.y;
                t[r + i * 16][c + 2] = (f16)v.z;
                t[r + i * 16][c + 3] = (f16)v.w;
            }
        }
        __syncthreads();
        {
            int c = tid >> 3;
            int rr = (tid & 7) * 8;
            int ch = rr >> 3;
#pragma unroll
            for (int i = 0; i < 2; i++) {
                int cc = c + i * 32;
                int rowi = c0 + cc;
                f16x8 o;
#pragma unroll
                for (int j = 0; j < 8; j++) o[j] = t[rr + j][cc];
                *(f16x8*)(dst + (size_t)rowi * R + r0 + (((ch ^ rowi) & 7) << 3)) = o;
            }
        }
    } else {
        int wv = tid >> 6, lane = tid & 63;
        int idx = (bid - CVT_BLKS) * 4 + wv;
        int e = idx >> 12, j = idx & (N_TOK - 1);
        int cnt;
        int off = prefix_off(counts, e, &cnt);
        if (j >= cnt) return;
        int id = list[idx];
        int row = off + j;
        const float* xr = x + (size_t)(id >> 1) * D_;
        f16* dst = xg + (size_t)row * D_;
        int r7 = row & 7;
#pragma unroll
        for (int c = 0; c < 3; c++) {
            int h = lane * 4 + c * 256;
            float4 v = *(const float4*)(xr + h);
            f16 o[4] = {(f16)v.x, (f16)v.y, (f16)v.z, (f16)v.w};
            int hs = (h & ~0x3F) | ((((h >> 3) ^ r7) & 7) << 3) | (h & 7);
            *(float2*)(dst + hs) = *(const float2*)o;
        }
    }
}

// ---------------- GEMM1 (R18-verified): 64x64x64, 2-barrier, gld_lds, XCD-pinned, L2-blocked ----------------
__global__ __launch_bounds__(256, 8) void gemm1(const f16* __restrict__ xg,
                                                const f16* __restrict__ w1t,
                                                const float* __restrict__ b1,
                                                const int* __restrict__ counts,
                                                f16* __restrict__ hbuf) {
    int bid = blockIdx.x;
    int e = bid & 7;
    int r = bid >> 3;
    int xb24 = r % 24;
    int yb = (r / 24) % 64;
    int xh = r / (24 * 64);
    int cnt;
    int off = prefix_off(counts, e, &cnt);
    int rb = yb * BT;
    if (rb >= cnt) return;
    int cb = (xh * 24 + xb24) * BT;

    __shared__ f16 lds[2 * BT * BK];
    char* ldsb = (char*)lds;

    int tid = threadIdx.x;
    int wv = tid >> 6, lane = tid & 63;
    int lr = lane >> 3, lc = lane & 7;

    int r0l = wv * 8 + lr;
    int r1l = 32 + wv * 8 + lr;
    int ag0 = off + rb + r0l; if (ag0 > 8191) ag0 = 8191;
    int ag1 = off + rb + r1l; if (ag1 > 8191) ag1 = 8191;
    const f16* ap0 = xg + (size_t)ag0 * D_ + lc * 8;
    const f16* ap1 = xg + (size_t)ag1 * D_ + lc * 8;
    const f16* wb = w1t + (size_t)e * H_ * D_;
    const f16* bp0 = wb + (size_t)(cb + r0l) * D_ + lc * 8;
    const f16* bp1 = wb + (size_t)(cb + r1l) * D_ + lc * 8;
    f16* la0 = lds + wv * 512;
    f16* la1 = lds + 2048 + wv * 512;
    f16* lb0 = lds + 4096 + wv * 512;
    f16* lb1 = lds + 6144 + wv * 512;

    int wr = (wv >> 1) * 32, wc = (wv & 1) * 32;
    int fr = lane & 15, qh = lane >> 4;
    int koff = (off + rb) & 7;

    int roA[2][2], roB[2][2];
#pragma unroll
    for (int m = 0; m < 2; m++)
#pragma unroll
        for (int ks = 0; ks < 2; ks++) {
            int row = wr + m * 16 + fr;
            roA[m][ks] = row * 128 + ((((ks * 4 + qh) ^ (koff + row)) & 7) << 4);
            int rwb = wc + m * 16 + fr;
            roB[m][ks] = 8192 + rwb * 128 + ((((ks * 4 + qh) ^ rwb) & 7) << 4);
        }

    f32x4 acc[2][2] = {};
    const int NT = D_ / BK;  // 12
#pragma unroll 1
    for (int t = 0; t < NT; ++t) {
        int kk = t * BK;
        gld16(ap0 + kk, la0);
        gld16(ap1 + kk, la1);
        gld16(bp0 + kk, lb0);
        gld16(bp1 + kk, lb1);
        __syncthreads();
#pragma unroll
        for (int ks = 0; ks < 2; ks++) {
            f16x8 a0 = *(const f16x8*)(ldsb + roA[0][ks]);
            f16x8 a1 = *(const f16x8*)(ldsb + roA[1][ks]);
            f16x8 b0 = *(const f16x8*)(ldsb + roB[0][ks]);
            f16x8 b1v = *(const f16x8*)(ldsb + roB[1][ks]);
            acc[0][0] = __builtin_amdgcn_mfma_f32_16x16x32_f16(a0, b0, acc[0][0], 0, 0, 0);
            acc[0][1] = __builtin_amdgcn_mfma_f32_16x16x32_f16(a0, b1v, acc[0][1], 0, 0, 0);
            acc[1][0] = __builtin_amdgcn_mfma_f32_16x16x32_f16(a1, b0, acc[1][0], 0, 0, 0);
            acc[1][1] = __builtin_amdgcn_mfma_f32_16x16x32_f16(a1, b1v, acc[1][1], 0, 0, 0);
        }
        __syncthreads();
    }

#pragma unroll
    for (int n = 0; n < 2; n++) {
        int colg = cb + wc + n * 16 + fr;
        float bias = b1[e * H_ + colg];
#pragma unroll
        for (int m = 0; m < 2; m++) {
#pragma unroll
            for (int r2 = 0; r2 < 4; r2++) {
                int j = rb + wr + m * 16 + qh * 4 + r2;
                if (j < cnt) {
                    float v = acc[m][n][r2] + bias;
                    v = 0.5f * v * (1.f + erff(v * 0.70710678f));
                    int row = off + j;
                    int hs = (colg & ~0x3F) | ((((colg >> 3) ^ row) & 7) << 3) | (colg & 7);
                    hbuf[(size_t)row * H_ + hs] = (f16)v;
                }
            }
        }
    }
}

// ---------------- GEMM2: 64x64x32, 2-deep counted-vmcnt pipeline, 16KB LDS, KSPLIT=1 ----------------
// LDS per buffer: A [0,2048) halfs, B [2048,4096); buffers at +0 / +4096 halfs.
// LDS chunk layout: local row rl's 64B holds logical 16B-chunk q2 at pos p=((q2^(rl&3))+(rl>>2))&3.
// Global format (prep/pack): logical chunk q (0..7) of row g at pos (q^(g&7)) in each 128B group.
__global__ __launch_bounds__(256, 8) void gemm2(const f16* __restrict__ hbuf,
                                                const f16* __restrict__ w2t,
                                                const float* __restrict__ b2,
                                                const int* __restrict__ counts,
                                                const int* __restrict__ list,
                                                const float* __restrict__ wslot,
                                                float* __restrict__ out) {
    int bid = blockIdx.x;
    int e = bid & 7;
    int r = bid >> 3;
    int cb12 = r % 12;
    int yb = r / 12;                 // 0..63
    int cnt;
    int off = prefix_off(counts, e, &cnt);
    int rb = yb * BT;
    if (rb >= cnt) return;
    int cb = cb12 * BT;

    __shared__ f16 lds[8192];        // 16 KB total (2 buffers x 8KB)
    char* ldsb = (char*)lds;

    int tid = threadIdx.x;
    int wv = tid >> 6, lane = tid & 63;

    // ---- staging setup: thread stages chunk c=tid for A and for B ----
    int rs = tid >> 2;               // local row 0..63
    int ps = tid & 3;                // LDS pos within row
    int q2s = ((ps - (rs >> 2)) & 3) ^ (rs & 3);   // logical chunk (0..3) this pos holds
    int agA = off + rb + rs; if (agA > 8191) agA = 8191;
    int posAe = q2s ^ (agA & 7);     // even-parity global pos (0..7)
    const f16* gA_e = hbuf + (size_t)agA * H_ + posAe * 8;
    const f16* gA_o = hbuf + (size_t)agA * H_ + (posAe ^ 4) * 8;
    int grB = cb + rs;               // (grB&7)==(rs&7) since cb%64==0
    int posBe = q2s ^ (rs & 7);
    const f16* gB_e = w2t + (size_t)e * D_ * H_ + (size_t)grB * H_ + posBe * 8;
    const f16* gB_o = w2t + (size_t)e * D_ * H_ + (size_t)grB * H_ + (posBe ^ 4) * 8;
    f16* ldA = lds + wv * 512;               // wave-uniform; lane lands at +lane*8 halfs
    f16* ldB = lds + 2048 + wv * 512;

    // ---- compute setup ----
    int wr = (wv >> 1) * 32, wc = (wv & 1) * 32;
    int fr = lane & 15, qh = lane >> 4;      // qh = logical chunk wanted (k-offset qh*8 of 32)

    int roA[2], roB[2];
#pragma unroll
    for (int m = 0; m < 2; m++) {
        int rl = wr + m * 16 + fr;
        int p = (((qh ^ (rl & 3)) + (rl >> 2)) & 3);
        roA[m] = rl * 64 + p * 16;                 // bytes
        int rlb = wc + m * 16 + fr;
        int pb = (((qh ^ (rlb & 3)) + (rlb >> 2)) & 3);
        roB[m] = 4096 + rlb * 64 + pb * 16;
    }

#define G2STG(tt, b) do {                                              \
    int g64 = ((tt) >> 1) * 64;                                        \
    const f16* pa_ = (((tt) & 1) ? gA_o : gA_e) + g64;                 \
    const f16* pb_ = (((tt) & 1) ? gB_o : gB_e) + g64;                 \
    gld16(pa_, ldA + (b) * 4096);                                      \
    gld16(pb_, ldB + (b) * 4096);                                      \
} while (0)

    f32x4 acc[2][2] = {};
    const int NT = H_ / 32;   // 96

    G2STG(0, 0);
    G2STG(1, 1);

#pragma unroll 1
    for (int t = 0; t < NT; ++t) {
        if (t + 1 < NT) asm volatile("s_waitcnt vmcnt(2)" ::: "memory");
        else            asm volatile("s_waitcnt vmcnt(0)" ::: "memory");
        __syncthreads();
        int bo = (t & 1) << 13;   // byte offset of compute buffer (8KB)
        f16x8 a0 = *(const f16x8*)(ldsb + bo + roA[0]);
        f16x8 a1 = *(const f16x8*)(ldsb + bo + roA[1]);
        f16x8 b0 = *(const f16x8*)(ldsb + bo + roB[0]);
        f16x8 b1v = *(const f16x8*)(ldsb + bo + roB[1]);
        acc[0][0] = __builtin_amdgcn_mfma_f32_16x16x32_f16(a0, b0, acc[0][0], 0, 0, 0);
        acc[0][1] = __builtin_amdgcn_mfma_f32_16x16x32_f16(a0, b1v, acc[0][1], 0, 0, 0);
        acc[1][0] = __builtin_amdgcn_mfma_f32_16x16x32_f16(a1, b0, acc[1][0], 0, 0, 0);
        acc[1][1] = __builtin_amdgcn_mfma_f32_16x16x32_f16(a1, b1v, acc[1][1], 0, 0, 0);
        __syncthreads();
        if (t + 2 < NT) G2STG(t + 2, t & 1);
    }

#pragma unroll
    for (int n = 0; n < 2; n++) {
        int colg = cb + wc + n * 16 + fr;
        float bias = b2[e * D_ + colg];
#pragma unroll
        for (int m = 0; m < 2; m++) {
#pragma unroll
            for (int r2 = 0; r2 < 4; r2++) {
                int j = rb + wr + m * 16 + qh * 4 + r2;
                if (j < cnt) {
                    int id = list[e * N_TOK + j];
                    float w = wslot[id];
                    float v = (acc[m][n][r2] + bias) * w;
                    atomicAdd(&out[(size_t)(id >> 1) * D_ + colg], v);
                }
            }
        }
    }
}

extern "C" void kernel_launch(void* const* d_in, const int* in_sizes, int n_in,
                              void* d_out, int out_size, void* d_ws, size_t ws_size,
                              hipStream_t stream) {
    const float* x = (const float*)d_in[0];
    const float* gate_w = (const float*)d_in[1];
    const float* gate_b = (const float*)d_in[2];
    const float* w1 = (const float*)d_in[3];
    const float* b1 = (const float*)d_in[4];
    const float* w2 = (const float*)d_in[5];
    const float* b2 = (const float*)d_in[6];
    float* out = (float*)d_out;

    char* ws = (char*)d_ws;
    int* counts = (int*)ws;                           // 32 B
    int* list = (int*)(ws + 1024);                    // 131072 B
    float* wslot = (float*)(ws + 132096);             // 32768 B
    f16* xg = (f16*)(ws + 196608);                    // 12582912 B
    f16* w1t = (f16*)(ws + 12779520);                 // 37748736 B
    f16* w2t = (f16*)(ws + 50528256);                 // 37748736 B
    f16* hbuf = (f16*)(ws + 88276992);                // 50331648 B

    hipMemsetAsync(counts, 0, 256, stream);
    hipMemsetAsync(out, 0, (size_t)out_size * sizeof(float), stream);

    router<<<64, 1024, 0, stream>>>(x, gate_w, gate_b, counts, list, wslot);
    prep<<<CVT_BLKS + E_ * N_TOK / 4, 256, 0, stream>>>(w1, w2, w1t, w2t, x, counts, list, xg);
    gemm1<<<E_ * 2 * 64 * 24, 256, 0, stream>>>(xg, w1t, b1, counts, hbuf);
    gemm2<<<E_ * 64 * 12, 256, 0, stream>>>(hbuf, w2t, b2, counts, list, wslot, out);
}

// Round 21
// 235.936 us; speedup vs baseline: 1.1532x; 1.1532x over previous
//
#include <hip/hip_runtime.h>
#include <hip/hip_bf16.h>

#define D_ 768
#define E_ 8
#define H_ 3072
#define N_TOK 4096
#define BT 64
#define BK 64

typedef _Float16 f16;
typedef f16 f16x8 __attribute__((ext_vector_type(8)));
typedef float f32x4 __attribute__((ext_vector_type(4)));

__device__ __forceinline__ void gld16(const f16* g, f16* l) {
    __builtin_amdgcn_global_load_lds(
        (const __attribute__((address_space(1))) unsigned int*)g,
        (__attribute__((address_space(3))) unsigned int*)l, 16, 0, 0);
}

__device__ __forceinline__ int prefix_off(const int* counts, int e, int* cnt_out) {
    int off = 0, cnt = 0;
#pragma unroll
    for (int q = 0; q < E_; q++) {
        int cq = counts[q];
        if (q < e) off += cq;
        if (q == e) cnt = cq;
    }
    *cnt_out = cnt;
    return off;
}

// ---------------- router: coalesced GEMV + LDS-aggregated atomics ----------------
__global__ __launch_bounds__(1024) void router(const float* __restrict__ x,
                                               const float* __restrict__ gw,
                                               const float* __restrict__ gb,
                                               int* __restrict__ counts,
                                               int* __restrict__ list,
                                               float* __restrict__ wslot) {
    __shared__ int lcount[E_];
    __shared__ int lbase[E_];
    __shared__ int te0[64], te1[64], ts0[64], ts1[64];
    __shared__ float tw0[64], tw1[64];

    int tid = threadIdx.x;
    int wv = tid >> 6, lane = tid & 63;
    int s = lane >> 3, eL = lane & 7;
    if (tid < E_) lcount[tid] = 0;
    __syncthreads();

    float biasL = gb[eL];

#pragma unroll 1
    for (int i = 0; i < 4; i++) {
        int lt = wv * 4 + i;
        int tok = blockIdx.x * 64 + lt;
        const float* xr = x + (size_t)tok * D_;
        float a = 0.f;
        const float* gwl = gw + lane;
#pragma unroll 8
        for (int j = 0; j < 96; j++)
            a = fmaf(xr[j * 8 + s], gwl[j * 64], a);
        a += __shfl_xor(a, 8, 64);
        a += __shfl_xor(a, 16, 64);
        a += __shfl_xor(a, 32, 64);
        float lg = a + biasL;
        float le[8];
#pragma unroll
        for (int q = 0; q < 8; q++) le[q] = __shfl(lg, q, 64);
        float v0 = -3.4e38f, v1 = -3.4e38f;
        int i0 = 0, i1 = 0;
#pragma unroll
        for (int q = 0; q < 8; q++) {
            float l = le[q];
            if (l > v0) { v1 = v0; i1 = i0; v0 = l; i0 = q; }
            else if (l > v1) { v1 = l; i1 = q; }
        }
        if (lane == 0) {
            float p1 = expf(v1 - v0);
            float ssum = 1.f + p1;
            int s0 = atomicAdd(&lcount[i0], 1);
            int s1 = atomicAdd(&lcount[i1], 1);
            te0[lt] = i0; ts0[lt] = s0; tw0[lt] = 1.f / ssum;
            te1[lt] = i1; ts1[lt] = s1; tw1[lt] = p1 / ssum;
        }
    }
    __syncthreads();
    if (tid < E_) lbase[tid] = atomicAdd(&counts[tid], lcount[tid]);
    __syncthreads();
    if (tid < 64) {
        int tok = blockIdx.x * 64 + tid;
        int e0 = te0[tid], e1 = te1[tid];
        list[e0 * N_TOK + lbase[e0] + ts0[tid]] = tok * 2;
        list[e1 * N_TOK + lbase[e1] + ts1[tid]] = tok * 2 + 1;
        wslot[tok * 2] = tw0[tid];
        wslot[tok * 2 + 1] = tw1[tid];
    }
}

// ---------------- prep: fused weight-convert (blocks 0..9215) + pack_a ----------------
#define CVT_BLKS 9216   // 576 * 16
__global__ __launch_bounds__(256) void prep(const float* __restrict__ w1,
                                            const float* __restrict__ w2,
                                            f16* __restrict__ w1t,
                                            f16* __restrict__ w2t,
                                            const float* __restrict__ x,
                                            const int* __restrict__ counts,
                                            const int* __restrict__ list,
                                            f16* __restrict__ xg) {
    __shared__ f16 t[64][66];
    int bid = blockIdx.x;
    int tid = threadIdx.x;

    if (bid < CVT_BLKS) {
        int z = bid / 576;
        int bx = bid % 576;
        const float* src; f16* dst; int R, C, xb, yb;
        if (z < E_) {
            src = w1 + (size_t)z * D_ * H_; dst = w1t + (size_t)z * D_ * H_;
            R = D_; C = H_; xb = bx % 48; yb = bx / 48;
        } else {
            src = w2 + (size_t)(z - E_) * H_ * D_; dst = w2t + (size_t)(z - E_) * H_ * D_;
            R = H_; C = D_; xb = bx % 12; yb = bx / 12;
        }
        int r0 = yb * 64, c0 = xb * 64;
        {
            int r = tid >> 4;
            int c = (tid & 15) * 4;
#pragma unroll
            for (int i = 0; i < 4; i++) {
                float4 v = *(const float4*)(src + (size_t)(r0 + r + i * 16) * C + (c0 + c));
                t[r + i * 16][c] = (f16)v.x;
                t[r + i * 16][c + 1] = (f16)v.y;
                t[r + i * 16][c + 2] = (f16)v.z;
                t[r + i * 16][c + 3] = (f16)v.w;
            }
        }
        __syncthreads();
        {
            int c = tid >> 3;
            int rr = (tid & 7) * 8;
            int ch = rr >> 3;
#pragma unroll
            for (int i = 0; i < 2; i++) {
                int cc = c + i * 32;
                int rowi = c0 + cc;
                f16x8 o;
#pragma unroll
                for (int j = 0; j < 8; j++) o[j] = t[rr + j][cc];
                *(f16x8*)(dst + (size_t)rowi * R + r0 + (((ch ^ rowi) & 7) << 3)) = o;
            }
        }
    } else {
        int wv = tid >> 6, lane = tid & 63;
        int idx = (bid - CVT_BLKS) * 4 + wv;
        int e = idx >> 12, j = idx & (N_TOK - 1);
        int cnt;
        int off = prefix_off(counts, e, &cnt);
        if (j >= cnt) return;
        int id = list[idx];
        int row = off + j;
        const float* xr = x + (size_t)(id >> 1) * D_;
        f16* dst = xg + (size_t)row * D_;
        int r7 = row & 7;
#pragma unroll
        for (int c = 0; c < 3; c++) {
            int h = lane * 4 + c * 256;
            float4 v = *(const float4*)(xr + h);
            f16 o[4] = {(f16)v.x, (f16)v.y, (f16)v.z, (f16)v.w};
            int hs = (h & ~0x3F) | ((((h >> 3) ^ r7) & 7) << 3) | (h & 7);
            *(float2*)(dst + hs) = *(const float2*)o;
        }
    }
}

// ---------------- GEMM1: h = gelu(xg @ w1 + b1), 64x64, gld_lds, XCD-pinned, L2-blocked ----------------
__global__ __launch_bounds__(256, 8) void gemm1(const f16* __restrict__ xg,
                                                const f16* __restrict__ w1t,
                                                const float* __restrict__ b1,
                                                const int* __restrict__ counts,
                                                f16* __restrict__ hbuf) {
    int bid = blockIdx.x;
    int e = bid & 7;
    int r = bid >> 3;
    int xb24 = r % 24;
    int yb = (r / 24) % 64;
    int xh = r / (24 * 64);
    int cnt;
    int off = prefix_off(counts, e, &cnt);
    int rb = yb * BT;
    if (rb >= cnt) return;
    int cb = (xh * 24 + xb24) * BT;

    __shared__ f16 lds[2 * BT * BK];
    char* ldsb = (char*)lds;

    int tid = threadIdx.x;
    int wv = tid >> 6, lane = tid & 63;
    int lr = lane >> 3, lc = lane & 7;

    int r0l = wv * 8 + lr;
    int r1l = 32 + wv * 8 + lr;
    int ag0 = off + rb + r0l; if (ag0 > 8191) ag0 = 8191;
    int ag1 = off + rb + r1l; if (ag1 > 8191) ag1 = 8191;
    const f16* ap0 = xg + (size_t)ag0 * D_ + lc * 8;
    const f16* ap1 = xg + (size_t)ag1 * D_ + lc * 8;
    const f16* wb = w1t + (size_t)e * H_ * D_;
    const f16* bp0 = wb + (size_t)(cb + r0l) * D_ + lc * 8;
    const f16* bp1 = wb + (size_t)(cb + r1l) * D_ + lc * 8;
    f16* la0 = lds + wv * 512;
    f16* la1 = lds + 2048 + wv * 512;
    f16* lb0 = lds + 4096 + wv * 512;
    f16* lb1 = lds + 6144 + wv * 512;

    int wr = (wv >> 1) * 32, wc = (wv & 1) * 32;
    int fr = lane & 15, qh = lane >> 4;
    int koff = (off + rb) & 7;

    int roA[2][2], roB[2][2];
#pragma unroll
    for (int m = 0; m < 2; m++)
#pragma unroll
        for (int ks = 0; ks < 2; ks++) {
            int row = wr + m * 16 + fr;
            roA[m][ks] = row * 128 + ((((ks * 4 + qh) ^ (koff + row)) & 7) << 4);
            int rwb = wc + m * 16 + fr;
            roB[m][ks] = 8192 + rwb * 128 + ((((ks * 4 + qh) ^ rwb) & 7) << 4);
        }

    f32x4 acc[2][2] = {};
    const int NT = D_ / BK;  // 12
#pragma unroll 1
    for (int t = 0; t < NT; ++t) {
        int kk = t * BK;
        gld16(ap0 + kk, la0);
        gld16(ap1 + kk, la1);
        gld16(bp0 + kk, lb0);
        gld16(bp1 + kk, lb1);
        __syncthreads();
#pragma unroll
        for (int ks = 0; ks < 2; ks++) {
            f16x8 a0 = *(const f16x8*)(ldsb + roA[0][ks]);
            f16x8 a1 = *(const f16x8*)(ldsb + roA[1][ks]);
            f16x8 b0 = *(const f16x8*)(ldsb + roB[0][ks]);
            f16x8 b1v = *(const f16x8*)(ldsb + roB[1][ks]);
            acc[0][0] = __builtin_amdgcn_mfma_f32_16x16x32_f16(a0, b0, acc[0][0], 0, 0, 0);
            acc[0][1] = __builtin_amdgcn_mfma_f32_16x16x32_f16(a0, b1v, acc[0][1], 0, 0, 0);
            acc[1][0] = __builtin_amdgcn_mfma_f32_16x16x32_f16(a1, b0, acc[1][0], 0, 0, 0);
            acc[1][1] = __builtin_amdgcn_mfma_f32_16x16x32_f16(a1, b1v, acc[1][1], 0, 0, 0);
        }
        __syncthreads();
    }

#pragma unroll
    for (int n = 0; n < 2; n++) {
        int colg = cb + wc + n * 16 + fr;
        float bias = b1[e * H_ + colg];
#pragma unroll
        for (int m = 0; m < 2; m++) {
#pragma unroll
            for (int r2 = 0; r2 < 4; r2++) {
                int j = rb + wr + m * 16 + qh * 4 + r2;
                if (j < cnt) {
                    float v = acc[m][n][r2] + bias;
                    v = 0.5f * v * (1.f + erff(v * 0.70710678f));
                    int row = off + j;
                    int hs = (colg & ~0x3F) | ((((colg >> 3) ^ row) & 7) << 3) | (colg & 7);
                    hbuf[(size_t)row * H_ + hs] = (f16)v;
                }
            }
        }
    }
}

// ---------------- GEMM2: y = (hbuf @ w2 + b2) * wslot, scatter-add; KSPLIT=1 ----------------
__global__ __launch_bounds__(256, 8) void gemm2(const f16* __restrict__ hbuf,
                                                const f16* __restrict__ w2t,
                                                const float* __restrict__ b2,
                                                const int* __restrict__ counts,
                                                const int* __restrict__ list,
                                                const float* __restrict__ wslot,
                                                float* __restrict__ out) {
    int bid = blockIdx.x;
    int e = bid & 7;
    int r = bid >> 3;
    int cb12 = r % 12;
    int yb = r / 12;                 // 0..63
    int cnt;
    int off = prefix_off(counts, e, &cnt);
    int rb = yb * BT;
    if (rb >= cnt) return;
    int cb = cb12 * BT;

    __shared__ f16 lds[2 * BT * BK];
    char* ldsb = (char*)lds;

    int tid = threadIdx.x;
    int wv = tid >> 6, lane = tid & 63;
    int lr = lane >> 3, lc = lane & 7;

    int r0l = wv * 8 + lr;
    int r1l = 32 + wv * 8 + lr;
    int ag0 = off + rb + r0l; if (ag0 > 8191) ag0 = 8191;
    int ag1 = off + rb + r1l; if (ag1 > 8191) ag1 = 8191;
    const f16* ap0 = hbuf + (size_t)ag0 * H_ + lc * 8;
    const f16* ap1 = hbuf + (size_t)ag1 * H_ + lc * 8;
    const f16* wb = w2t + (size_t)e * D_ * H_;
    const f16* bp0 = wb + (size_t)(cb + r0l) * H_ + lc * 8;
    const f16* bp1 = wb + (size_t)(cb + r1l) * H_ + lc * 8;
    f16* la0 = lds + wv * 512;
    f16* la1 = lds + 2048 + wv * 512;
    f16* lb0 = lds + 4096 + wv * 512;
    f16* lb1 = lds + 6144 + wv * 512;

    int wr = (wv >> 1) * 32, wc = (wv & 1) * 32;
    int fr = lane & 15, qh = lane >> 4;
    int koff = (off + rb) & 7;

    int roA[2][2], roB[2][2];
#pragma unroll
    for (int m = 0; m < 2; m++)
#pragma unroll
        for (int ks = 0; ks < 2; ks++) {
            int row = wr + m * 16 + fr;
            roA[m][ks] = row * 128 + ((((ks * 4 + qh) ^ (koff + row)) & 7) << 4);
            int rwb = wc + m * 16 + fr;
            roB[m][ks] = 8192 + rwb * 128 + ((((ks * 4 + qh) ^ rwb) & 7) << 4);
        }

    f32x4 acc[2][2] = {};
    const int NT = H_ / BK;  // 48
#pragma unroll 1
    for (int t = 0; t < NT; ++t) {
        int kk = t * BK;
        gld16(ap0 + kk, la0);
        gld16(ap1 + kk, la1);
        gld16(bp0 + kk, lb0);
        gld16(bp1 + kk, lb1);
        __syncthreads();
#pragma unroll
        for (int ks = 0; ks < 2; ks++) {
            f16x8 a0 = *(const f16x8*)(ldsb + roA[0][ks]);
            f16x8 a1 = *(const f16x8*)(ldsb + roA[1][ks]);
            f16x8 b0 = *(const f16x8*)(ldsb + roB[0][ks]);
            f16x8 b1v = *(const f16x8*)(ldsb + roB[1][ks]);
            acc[0][0] = __builtin_amdgcn_mfma_f32_16x16x32_f16(a0, b0, acc[0][0], 0, 0, 0);
            acc[0][1] = __builtin_amdgcn_mfma_f32_16x16x32_f16(a0, b1v, acc[0][1], 0, 0, 0);
            acc[1][0] = __builtin_amdgcn_mfma_f32_16x16x32_f16(a1, b0, acc[1][0], 0, 0, 0);
            acc[1][1] = __builtin_amdgcn_mfma_f32_16x16x32_f16(a1, b1v, acc[1][1], 0, 0, 0);
        }
        __syncthreads();
    }

#pragma unroll
    for (int n = 0; n < 2; n++) {
        int colg = cb + wc + n * 16 + fr;
        float bias = b2[e * D_ + colg];
#pragma unroll
        for (int m = 0; m < 2; m++) {
#pragma unroll
            for (int r2 = 0; r2 < 4; r2++) {
                int j = rb + wr + m * 16 + qh * 4 + r2;
                if (j < cnt) {
                    int id = list[e * N_TOK + j];
                    float w = wslot[id];
                    float v = (acc[m][n][r2] + bias) * w;
                    atomicAdd(&out[(size_t)(id >> 1) * D_ + colg], v);
                }
            }
        }
    }
}

extern "C" void kernel_launch(void* const* d_in, const int* in_sizes, int n_in,
                              void* d_out, int out_size, void* d_ws, size_t ws_size,
                              hipStream_t stream) {
    const float* x = (const float*)d_in[0];
    const float* gate_w = (const float*)d_in[1];
    const float* gate_b = (const float*)d_in[2];
    const float* w1 = (const float*)d_in[3];
    const float* b1 = (const float*)d_in[4];
    const float* w2 = (const float*)d_in[5];
    const float* b2 = (const float*)d_in[6];
    float* out = (float*)d_out;

    char* ws = (char*)d_ws;
    int* counts = (int*)ws;                           // 32 B
    int* list = (int*)(ws + 1024);                    // 131072 B
    float* wslot = (float*)(ws + 132096);             // 32768 B
    f16* xg = (f16*)(ws + 196608);                    // 12582912 B
    f16* w1t = (f16*)(ws + 12779520);                 // 37748736 B
    f16* w2t = (f16*)(ws + 50528256);                 // 37748736 B
    f16* hbuf = (f16*)(ws + 88276992);                // 50331648 B

    hipMemsetAsync(counts, 0, 256, stream);
    hipMemsetAsync(out, 0, (size_t)out_size * sizeof(float), stream);

    router<<<64, 1024, 0, stream>>>(x, gate_w, gate_b, counts, list, wslot);
    prep<<<CVT_BLKS + E_ * N_TOK / 4, 256, 0, stream>>>(w1, w2, w1t, w2t, x, counts, list, xg);
    gemm1<<<E_ * 2 * 64 * 24, 256, 0, stream>>>(xg, w1t, b1, counts, hbuf);
    gemm2<<<E_ * 64 * 12, 256, 0, stream>>>(hbuf, w2t, b2, counts, list, wslot, out);
}